// Round 9
// baseline (140.475 us; speedup 1.0000x reference)
//
#include <hip/hip_runtime.h>

// LowFreqPenaltyLoss: mean(|truncated 2-D DCT (8x8) of each 256x256 image|)
// delta: [256,3,256,256] f32 -> scalar f32.
// Basis C[k,n] = 2*cos(pi*(2n+1)*k/512), identical for H and W.
// Per image: u[w][i] = sum_h C[i,h]*X[h,w]; low[i,j] = sum_w C[j,w]*u[w][i].
//
// R9 = R4's exact main body (1536 half-image blocks, butterfly epilogue,
// dword stride-64 loads, (256,3) bounds — best measured, 40.5us) with the
// reduce kernel FUSED via per-image winner pairing (R6's scheme, which was
// numerically correct; R6's 141us was the (256,4) spill pathology, not the
// fences). Second-arriving half-block pairs+abs+accumulates into a ws
// accumulator; the 768th winner stores out. Saves the 192-block reduce
// dispatch + 393KB ws re-read (~4-5us serial).

#define INV_COUNT (1.0f / 49152.0f)  // 256*3*8*8
#define NBLK 1536
#define CTRL_OFF (NBLK * 64)         // float index of control region in ws
// ctrl (770 words, memset 0 each launch): [0..767] int pair-counter per
// image, [768] float accum, [769] int done-counter.

__global__ __launch_bounds__(256, 3) void lowfreq_main(
    const float* __restrict__ delta, float* __restrict__ ws,
    float* __restrict__ out)
{
    __shared__ float c_row[256][8];  // basis, wave-uniform broadcast by row h
    __shared__ float c_col[8][256];  // transposed, per-lane epilogue reads
    __shared__ float pacc[4][64];

    const int t = threadIdx.x;
    const int wave = t >> 6;
    const int lane = t & 63;
    const int bid = blockIdx.x;
    const int img = bid >> 1;        // (n,c) image index
    const int half = bid & 1;        // rows [0,128) or [128,256)

    // Phase 0: DCT-II basis row t via Chebyshev recurrence (1 cosf).
    {
        const float a = 3.14159265358979323846f * (2.0f * (float)t + 1.0f)
                        * (1.0f / 512.0f);
        const float ca = cosf(a);
        float ckm1 = 1.0f, ck = ca;
        c_row[t][0] = 2.0f;       c_col[0][t] = 2.0f;
        c_row[t][1] = 2.0f * ca;  c_col[1][t] = 2.0f * ca;
        #pragma unroll
        for (int k = 2; k < 8; ++k) {
            const float cn = 2.0f * ca * ck - ckm1;
            ckm1 = ck; ck = cn;
            c_row[t][k] = 2.0f * cn;
            c_col[k][t] = 2.0f * cn;
        }
    }
    __syncthreads();

    // Phase 1: wave streams rows [half*128 + 32*wave, +32); thread owns
    // columns {lane, lane+64, lane+128, lane+192} (dword loads, stride 64 —
    // the pattern that benched fastest across R0-R8).
    const int row0 = (half << 7) + (wave << 5);
    const float* gp = delta + (size_t)img * 65536 + (size_t)row0 * 256 + lane;

    float u[4][8];
    #pragma unroll
    for (int c = 0; c < 4; ++c)
        #pragma unroll
        for (int i = 0; i < 8; ++i) u[c][i] = 0.0f;

    #pragma unroll 4
    for (int r = 0; r < 32; ++r) {
        const int h = row0 + r;
        const float x0 = gp[r * 256 + 0];
        const float x1 = gp[r * 256 + 64];
        const float x2 = gp[r * 256 + 128];
        const float x3 = gp[r * 256 + 192];
        const float4 cA = *reinterpret_cast<const float4*>(&c_row[h][0]);
        const float4 cB = *reinterpret_cast<const float4*>(&c_row[h][4]);
        const float cc[8] = {cA.x, cA.y, cA.z, cA.w, cB.x, cB.y, cB.z, cB.w};
        #pragma unroll
        for (int i = 0; i < 8; ++i) {
            u[0][i] = fmaf(cc[i], x0, u[0][i]);
            u[1][i] = fmaf(cc[i], x1, u[1][i]);
            u[2][i] = fmaf(cc[i], x2, u[2][i]);
            u[3][i] = fmaf(cc[i], x3, u[3][i]);
        }
    }

    // Phase 2: per-thread partial low[i][j] over its 4 columns (w = c*64+lane).
    float cw[4][8];
    #pragma unroll
    for (int c = 0; c < 4; ++c)
        #pragma unroll
        for (int j = 0; j < 8; ++j)
            cw[c][j] = c_col[j][(c << 6) + lane];

    float v[64];
    #pragma unroll
    for (int i = 0; i < 8; ++i)
        #pragma unroll
        for (int j = 0; j < 8; ++j) {
            float s = u[0][i] * cw[0][j];
            s = fmaf(u[1][i], cw[1][j], s);
            s = fmaf(u[2][i], cw[2][j], s);
            s = fmaf(u[3][i], cw[3][j], s);
            v[(i << 3) + j] = s;
        }

    // Phase 3: slot-splitting butterfly — transpose+reduce 64 slots across
    // the wave; lane l ends with the wave total of slot l = (i<<3|j).
    #pragma unroll
    for (int s = 0; s < 6; ++s) {
        const int m = 1 << s;
        const bool bit = (lane & m) != 0;
        #pragma unroll
        for (int k = 0; k < (64 >> (s + 1)); ++k) {
            const float a = v[2 * k];
            const float b = v[2 * k + 1];
            const float keep = bit ? b : a;
            const float send = bit ? a : b;
            const float recv = __shfl_xor(send, m, 64);
            v[k] = keep + recv;
        }
    }

    pacc[wave][lane] = v[0];
    __syncthreads();

    // Phase 4: wave 0 combines waves -> pre-abs half-image partial -> ws;
    // second-arriving block per image pairs, abs's, accumulates; the 768th
    // winner publishes out. (Scheme numerically verified in R6.)
    if (wave == 0) {
        const float s4 = pacc[0][lane] + pacc[1][lane]
                       + pacc[2][lane] + pacc[3][lane];
        ws[(size_t)bid * 64 + lane] = s4;
        __threadfence();                       // release partials
        int arrived = 0;
        if (lane == 0)
            arrived = atomicAdd((int*)(ws + CTRL_OFF) + img, 1);
        arrived = __shfl(arrived, 0, 64);
        if (arrived == 1) {                    // winner: sibling visible
            __threadfence();                   // acquire
            const float oth = ws[(size_t)(bid ^ 1) * 64 + lane];
            float a = fabsf(s4 + oth);
            #pragma unroll
            for (int m = 1; m < 64; m <<= 1) a += __shfl_xor(a, m, 64);
            if (lane == 0) {
                float* accum = ws + CTRL_OFF + 768;
                int* done = (int*)(ws + CTRL_OFF) + 769;
                atomicAdd(accum, a * INV_COUNT);
                __threadfence();
                if (atomicAdd(done, 1) == 767) {   // last winner: publish
                    __threadfence();
                    out[0] = atomicAdd(accum, 0.0f);
                }
            }
        }
    }
}

extern "C" void kernel_launch(void* const* d_in, const int* in_sizes, int n_in,
                              void* d_out, int out_size, void* d_ws, size_t ws_size,
                              hipStream_t stream)
{
    const float* delta = (const float*)d_in[0];
    float* out = (float*)d_out;
    float* ws = (float*)d_ws;  // partials 393216 B + 3080 B control
    hipMemsetAsync((char*)d_ws + (size_t)CTRL_OFF * 4, 0, 770 * 4, stream);
    lowfreq_main<<<NBLK, 256, 0, stream>>>(delta, ws, out);
}

// Round 10
// 40.943 us; speedup vs baseline: 3.4310x; 3.4310x over previous
//
#include <hip/hip_runtime.h>

// LowFreqPenaltyLoss: mean(|truncated 2-D DCT (8x8) of each 256x256 image|)
// delta: [256,3,256,256] f32 -> scalar f32.
// Basis C[k,n] = 2*cos(pi*(2n+1)*k/512), identical for H and W.
// Per image: u[w][i] = sum_h C[i,h]*X[h,w]; low[i,j] = sum_w C[j,w]*u[w][i].
//
// R10 = R4 restored verbatim (best measured: 40.48us). 1536 half-image
// blocks, dword stride-64 loads, butterfly epilogue, pre-abs partials to ws,
// 192-block pair+abs+sum reduce kernel.
// Established negative results (do NOT reintroduce):
//  - fence/winner fusion of the finish (R6/R9): VGPR collapse to 44/56 +
//    ~230us dispatches — allocator pathology + serialized agent-scope fences.
//  - __launch_bounds__ min-waves arg (R6): spill trap.
//  - float4 / batched-load / pipelined variants (R1/R5/R8): neutral or worse.
//  - single-kernel 768-block full-image (R0/R7): grid caps residency, ~48us.

#define INV_COUNT (1.0f / 49152.0f)  // 256*3*8*8

__global__ __launch_bounds__(256, 3) void lowfreq_main(
    const float* __restrict__ delta, float* __restrict__ ws,
    float* __restrict__ out)
{
    __shared__ float c_row[256][8];  // basis, wave-uniform broadcast by row h
    __shared__ float c_col[8][256];  // transposed, per-lane epilogue reads
    __shared__ float pacc[4][64];

    const int t = threadIdx.x;
    const int wave = t >> 6;
    const int lane = t & 63;
    const int bid = blockIdx.x;
    const int img = bid >> 1;        // (n,c) image index
    const int half = bid & 1;        // rows [0,128) or [128,256)

    // Phase 0: DCT-II basis row t via Chebyshev recurrence (1 cosf).
    {
        const float a = 3.14159265358979323846f * (2.0f * (float)t + 1.0f)
                        * (1.0f / 512.0f);
        const float ca = cosf(a);
        float ckm1 = 1.0f, ck = ca;
        c_row[t][0] = 2.0f;       c_col[0][t] = 2.0f;
        c_row[t][1] = 2.0f * ca;  c_col[1][t] = 2.0f * ca;
        #pragma unroll
        for (int k = 2; k < 8; ++k) {
            const float cn = 2.0f * ca * ck - ckm1;
            ckm1 = ck; ck = cn;
            c_row[t][k] = 2.0f * cn;
            c_col[k][t] = 2.0f * cn;
        }
    }
    __syncthreads();

    // Phase 1: wave streams rows [half*128 + 32*wave, +32); thread owns
    // columns {lane, lane+64, lane+128, lane+192} (dword loads, stride 64 —
    // the pattern that benched fastest across R0-R8).
    const int row0 = (half << 7) + (wave << 5);
    const float* gp = delta + (size_t)img * 65536 + (size_t)row0 * 256 + lane;

    float u[4][8];
    #pragma unroll
    for (int c = 0; c < 4; ++c)
        #pragma unroll
        for (int i = 0; i < 8; ++i) u[c][i] = 0.0f;

    #pragma unroll 4
    for (int r = 0; r < 32; ++r) {
        const int h = row0 + r;
        const float x0 = gp[r * 256 + 0];
        const float x1 = gp[r * 256 + 64];
        const float x2 = gp[r * 256 + 128];
        const float x3 = gp[r * 256 + 192];
        const float4 cA = *reinterpret_cast<const float4*>(&c_row[h][0]);
        const float4 cB = *reinterpret_cast<const float4*>(&c_row[h][4]);
        const float cc[8] = {cA.x, cA.y, cA.z, cA.w, cB.x, cB.y, cB.z, cB.w};
        #pragma unroll
        for (int i = 0; i < 8; ++i) {
            u[0][i] = fmaf(cc[i], x0, u[0][i]);
            u[1][i] = fmaf(cc[i], x1, u[1][i]);
            u[2][i] = fmaf(cc[i], x2, u[2][i]);
            u[3][i] = fmaf(cc[i], x3, u[3][i]);
        }
    }

    // Phase 2: per-thread partial low[i][j] over its 4 columns (w = c*64+lane).
    float cw[4][8];
    #pragma unroll
    for (int c = 0; c < 4; ++c)
        #pragma unroll
        for (int j = 0; j < 8; ++j)
            cw[c][j] = c_col[j][(c << 6) + lane];

    float v[64];
    #pragma unroll
    for (int i = 0; i < 8; ++i)
        #pragma unroll
        for (int j = 0; j < 8; ++j) {
            float s = u[0][i] * cw[0][j];
            s = fmaf(u[1][i], cw[1][j], s);
            s = fmaf(u[2][i], cw[2][j], s);
            s = fmaf(u[3][i], cw[3][j], s);
            v[(i << 3) + j] = s;
        }

    // Phase 3: slot-splitting butterfly — transpose+reduce 64 slots across the
    // wave; at the end lane l holds the wave total of slot l = (i<<3|j).
    #pragma unroll
    for (int s = 0; s < 6; ++s) {
        const int m = 1 << s;
        const bool bit = (lane & m) != 0;
        #pragma unroll
        for (int k = 0; k < (64 >> (s + 1)); ++k) {
            const float a = v[2 * k];
            const float b = v[2 * k + 1];
            const float keep = bit ? b : a;
            const float send = bit ? a : b;
            const float recv = __shfl_xor(send, m, 64);
            v[k] = keep + recv;
        }
    }

    pacc[wave][lane] = v[0];
    __syncthreads();

    // Phase 4: combine 4 waves; write PRE-ABS half-image partials to ws.
    if (t < 64) {
        const float s4 = pacc[0][t] + pacc[1][t] + pacc[2][t] + pacc[3][t];
        ws[(size_t)bid * 64 + t] = s4;
        if (bid == 0 && t == 0) out[0] = 0.0f;  // stream-ordered before reduce
    }
}

// Pair the two half-image partials, abs, sum all 49152 slots into out.
__global__ __launch_bounds__(256) void lowfreq_reduce(
    const float* __restrict__ ws, float* __restrict__ out)
{
    __shared__ float acc[4];
    const int t = threadIdx.x;
    const int wave = t >> 6;
    const int lane = t & 63;
    const int g = blockIdx.x * 256 + t;       // 192*256 = 49152 = 768*64
    const int img = g >> 6;
    const int slot = g & 63;

    const float s = ws[(size_t)(2 * img) * 64 + slot]
                  + ws[(size_t)(2 * img + 1) * 64 + slot];
    float a = fabsf(s);
    #pragma unroll
    for (int m = 1; m < 64; m <<= 1) a += __shfl_xor(a, m, 64);
    if (lane == 0) acc[wave] = a;
    __syncthreads();
    if (t == 0)
        atomicAdd(out, (acc[0] + acc[1] + acc[2] + acc[3]) * INV_COUNT);
}

extern "C" void kernel_launch(void* const* d_in, const int* in_sizes, int n_in,
                              void* d_out, int out_size, void* d_ws, size_t ws_size,
                              hipStream_t stream)
{
    const float* delta = (const float*)d_in[0];
    float* out = (float*)d_out;
    float* ws = (float*)d_ws;  // 1536*64*4 B = 393 KB
    lowfreq_main<<<1536, 256, 0, stream>>>(delta, ws, out);
    lowfreq_reduce<<<192, 256, 0, stream>>>(ws, out);
}